// Round 15
// baseline (192.858 us; speedup 1.0000x reference)
//
#include <hip/hip_runtime.h>
#include <hip/hip_bf16.h>
#include <hip/hip_fp8.h>

#define B_SZ 8192
#define D_SZ 256          // elements per row; fp8 row = 256 B
#define NTILES 2080       // (8192/128)*(8192/128+1)/2 upper-tri tiles
#define GRID_SIM 512      // persistent, 2 blocks/CU (VGPR-limited)
// rows pre-scaled by sqrt(log2(e)/T): exp2(acc) == exp(sim/T)
#define PRESCALE 4.539816004686735f

typedef __attribute__((ext_vector_type(4))) float f32x4;

// ---------------- L2-normalize rows, scale, cast to FP8 e4m3 (+ zero sums) -
__global__ __launch_bounds__(256) void norm_kernel(const float* __restrict__ emb,
                                                   unsigned char* __restrict__ nq,
                                                   float* __restrict__ sums) {
    // zero all_sum+pos_sum: 16384 floats over 256 blocks
    sums[blockIdx.x * 64 + (threadIdx.x >> 2)] = 0.0f;

    const int wave = threadIdx.x >> 6, lane = threadIdx.x & 63;
    for (int g = blockIdx.x; g < B_SZ / 4; g += 256) {
        const int row = g * 4 + wave;
        const float4 v = ((const float4*)(emb + (size_t)row * D_SZ))[lane];
        float ss = v.x * v.x + v.y * v.y + v.z * v.z + v.w * v.w;
        #pragma unroll
        for (int m = 1; m < 64; m <<= 1) ss += __shfl_xor(ss, m, 64);
        float s = PRESCALE / fmaxf(sqrtf(ss), 1e-12f);
        __hip_fp8_e4m3 q0(v.x * s), q1(v.y * s), q2(v.z * s), q3(v.w * s);
        uchar4 o;
        o.x = q0.__x; o.y = q1.__x; o.z = q2.__x; o.w = q3.__x;
        ((uchar4*)(nq + (size_t)row * D_SZ))[lane] = o;
    }
}

// ---------------- helpers ---------------------------------------------------
__device__ __forceinline__ void decode_tile(int tb, int& i0, int& j0, bool& diag) {
    int bj = (int)((sqrtf(8.0f * tb + 1.0f) - 1.0f) * 0.5f);
    while ((bj + 1) * (bj + 2) / 2 <= tb) ++bj;
    while (bj * (bj + 1) / 2 > tb) --bj;
    const int bi = tb - bj * (bj + 1) / 2;
    i0 = bi * 128; j0 = bj * 128; diag = (bi == bj);
}

// Load a full-K (256B) 64x64-panel fragment set straight from global (L2/L1
// resident). fp8 16x16x32 A-operand: lane holds 8B at row (lane&15),
// byte kb*32 + (lane>>4)*8. 32 independent dwordx2 loads, no LDS.
__device__ __forceinline__ void load_frags(long long frag[4][8],
                                           const unsigned char* __restrict__ base,
                                           int lane) {
    const int lr = lane & 15;
    const int q8 = (lane >> 4) * 8;
    #pragma unroll
    for (int f = 0; f < 4; ++f) {
        const unsigned char* rp = base + (size_t)(f * 16 + lr) * D_SZ + q8;
        #pragma unroll
        for (int kb = 0; kb < 8; ++kb)
            frag[f][kb] = *(const long long*)(rp + kb * 32);
    }
}

// ---------------- fused sim: all-register full-K quadrants, no LDS ---------
// Each wave owns a 64x64 quadrant. Per tile: ONE batch of 64 loads -> 128
// MFMAs -> prefetch next tile's fragments into the dead regs -> epilogue
// (~2k cyc) ages prefetch + atomics -> single implicit vmcnt wait per tile.
__global__ __launch_bounds__(256) void sim_kernel(const unsigned char* __restrict__ N,
                                                  const int* __restrict__ ids,
                                                  float* __restrict__ all_sum,
                                                  float* __restrict__ pos_sum) {
    const int t    = threadIdx.x;
    const int wave = t >> 6, lane = t & 63;
    const int wy   = wave >> 1, wx = wave & 1;
    const int myc  = lane & 15;

    int tb = blockIdx.x;
    int i0, j0; bool diag;
    decode_tile(tb, i0, j0, diag);

    long long a_frag[4][8], b_frag[4][8];
    load_frags(a_frag, N + (size_t)(i0 + wy * 64) * D_SZ, lane);
    load_frags(b_frag, N + (size_t)(j0 + wx * 64) * D_SZ, lane);

    while (true) {
        const int R0 = i0 + wy * 64;
        const int C0 = j0 + wx * 64;
        const bool d_quad = diag && (wy == wx);

        f32x4 acc[4][4];
        #pragma unroll
        for (int mi = 0; mi < 4; ++mi)
            #pragma unroll
            for (int ni = 0; ni < 4; ++ni)
                acc[mi][ni] = (f32x4){0.f, 0.f, 0.f, 0.f};

        #pragma unroll
        for (int kb = 0; kb < 8; ++kb)
            #pragma unroll
            for (int mi = 0; mi < 4; ++mi)
                #pragma unroll
                for (int ni = 0; ni < 4; ++ni)
                    acc[mi][ni] = __builtin_amdgcn_mfma_f32_16x16x32_fp8_fp8(
                        a_frag[mi][kb], b_frag[ni][kb], acc[mi][ni], 0, 0, 0);

        // prefetch NEXT tile's fragments into the (now dead) frag regs;
        // the epilogue below ages their latency.
        const int ntb = tb + GRID_SIM;
        const bool have_next = (ntb < NTILES);
        int ni0 = i0, nj0 = j0; bool ndiag = diag;
        if (have_next) {
            decode_tile(ntb, ni0, nj0, ndiag);
            load_frags(a_frag, N + (size_t)(ni0 + wy * 64) * D_SZ, lane);
            load_frags(b_frag, N + (size_t)(nj0 + wx * 64) * D_SZ, lane);
        }

        // ---- epilogue (registers + shuffles + global atomics) ----
        // C/D map: col=lane&15, row=(lane>>4)*4+reg (quadrant-local)
        int idc[4];
        #pragma unroll
        for (int ni = 0; ni < 4; ++ni)
            idc[ni] = ids[C0 + ni * 16 + myc];

        float cAll[4] = {0.f, 0.f, 0.f, 0.f};
        float cPos[4] = {0.f, 0.f, 0.f, 0.f};

        #pragma unroll
        for (int mi = 0; mi < 4; ++mi) {
            const int rb = mi * 16 + (lane >> 4) * 4;
            const int4 idr = *(const int4*)&ids[R0 + rb];
            float rAll[4] = {0.f, 0.f, 0.f, 0.f};
            float rPos[4] = {0.f, 0.f, 0.f, 0.f};
            #pragma unroll
            for (int ni = 0; ni < 4; ++ni) {
                #pragma unroll
                for (int rg = 0; rg < 4; ++rg) {
                    float e = __builtin_amdgcn_exp2f(acc[mi][ni][rg]);
                    if (d_quad && (rb + rg) == (ni * 16 + myc)) e = 0.0f;  // diag
                    rAll[rg] += e; cAll[ni] += e;
                    const int idrv = (rg == 0) ? idr.x : (rg == 1) ? idr.y
                                   : (rg == 2) ? idr.z : idr.w;
                    if (idrv == idc[ni]) { rPos[rg] += e; cPos[ni] += e; }
                }
            }
            #pragma unroll
            for (int rg = 0; rg < 4; ++rg) {
                #pragma unroll
                for (int mm = 1; mm < 16; mm <<= 1) {
                    rAll[rg] += __shfl_xor(rAll[rg], mm, 64);
                    rPos[rg] += __shfl_xor(rPos[rg], mm, 64);
                }
            }
            if (myc == 0) {
                #pragma unroll
                for (int rg = 0; rg < 4; ++rg) {
                    atomicAdd(&all_sum[R0 + rb + rg], rAll[rg]);
                    if (rPos[rg] != 0.0f) atomicAdd(&pos_sum[R0 + rb + rg], rPos[rg]);
                }
            }
        }

        // column sums -> rows j (off-diagonal tiles only; symmetry)
        if (!diag) {
            #pragma unroll
            for (int ni = 0; ni < 4; ++ni) {
                cAll[ni] += __shfl_xor(cAll[ni], 16, 64);
                cAll[ni] += __shfl_xor(cAll[ni], 32, 64);
                cPos[ni] += __shfl_xor(cPos[ni], 16, 64);
                cPos[ni] += __shfl_xor(cPos[ni], 32, 64);
            }
            if (lane < 16) {
                #pragma unroll
                for (int ni = 0; ni < 4; ++ni) {
                    atomicAdd(&all_sum[C0 + ni * 16 + lane], cAll[ni]);
                    if (cPos[ni] != 0.0f) atomicAdd(&pos_sum[C0 + ni * 16 + lane], cPos[ni]);
                }
            }
        }

        if (!have_next) break;
        tb = ntb; i0 = ni0; j0 = nj0; diag = ndiag;
    }
}

// ---------------- final scalar reduce ----------------
__global__ __launch_bounds__(256) void loss_kernel(const float* __restrict__ all_sum,
                                                   const float* __restrict__ pos_sum,
                                                   float* __restrict__ out) {
    float loss = 0.0f, cnt = 0.0f;
    for (int i = threadIdx.x; i < B_SZ; i += 256) {
        float p = pos_sum[i], a = all_sum[i];
        if (p > 0.0f) { loss += logf(a) - logf(p); cnt += 1.0f; }
    }
    #pragma unroll
    for (int m = 1; m < 64; m <<= 1) {
        loss += __shfl_xor(loss, m, 64);
        cnt  += __shfl_xor(cnt, m, 64);
    }
    __shared__ float sl[4], sc[4];
    int wave = threadIdx.x >> 6, lane = threadIdx.x & 63;
    if (lane == 0) { sl[wave] = loss; sc[wave] = cnt; }
    __syncthreads();
    if (threadIdx.x == 0) {
        float L = sl[0] + sl[1] + sl[2] + sl[3];
        float C = sc[0] + sc[1] + sc[2] + sc[3];
        out[0] = L / fmaxf(C, 1.0f);
    }
}

extern "C" void kernel_launch(void* const* d_in, const int* in_sizes, int n_in,
                              void* d_out, int out_size, void* d_ws, size_t ws_size,
                              hipStream_t stream) {
    const float* emb = (const float*)d_in[0];
    const int*   ids = (const int*)d_in[1];
    float*       out = (float*)d_out;

    float*         all_sum = (float*)d_ws;
    float*         pos_sum = all_sum + B_SZ;
    unsigned char* nq      = (unsigned char*)d_ws + 65536;   // 8192*256 fp8 = 2 MB

    norm_kernel<<<256, 256, 0, stream>>>(emb, nq, all_sum);
    sim_kernel<<<GRID_SIM, 256, 0, stream>>>(nq, ids, all_sum, pos_sum);
    loss_kernel<<<1, 256, 0, stream>>>(all_sum, pos_sum, out);
}

// Round 16
// 152.100 us; speedup vs baseline: 1.2680x; 1.2680x over previous
//
#include <hip/hip_runtime.h>
#include <hip/hip_bf16.h>

#define B_SZ 8192
#define D_SZ 256
#define NTILES2 1056    // sum over bi=0..63 of (32 - bi/2): 128x256 upper tiles
#define GRID_SIM 512    // persistent
// rows pre-scaled by sqrt(log2(e)/T): exp2(acc) == exp(sim/T)
#define PRESCALE 4.539816004686735f

typedef __attribute__((ext_vector_type(4))) float f32x4;
typedef __attribute__((ext_vector_type(8))) short s16x8;

// ---- async global->LDS, 16B per lane (wave-uniform LDS base + lane*16) ----
__device__ __forceinline__ void async_copy16(const void* g, void* l) {
    __builtin_amdgcn_global_load_lds(
        (const __attribute__((address_space(1))) unsigned int*)g,
        (__attribute__((address_space(3))) unsigned int*)l,
        16, 0, 0);
}

// ---------------- L2-normalize rows, scale, cast to bf16 (+ zero sums) -----
__global__ __launch_bounds__(256) void norm_kernel(const float* __restrict__ emb,
                                                   ushort* __restrict__ nbf,
                                                   float* __restrict__ sums) {
    // zero all_sum+pos_sum: 16384 floats over 256 blocks
    sums[blockIdx.x * 64 + (threadIdx.x >> 2)] = 0.0f;

    const int wave = threadIdx.x >> 6, lane = threadIdx.x & 63;
    for (int g = blockIdx.x; g < B_SZ / 4; g += 256) {
        const int row = g * 4 + wave;
        const float4 v = ((const float4*)(emb + (size_t)row * D_SZ))[lane];
        float ss = v.x * v.x + v.y * v.y + v.z * v.z + v.w * v.w;
        #pragma unroll
        for (int m = 1; m < 64; m <<= 1) ss += __shfl_xor(ss, m, 64);
        float s = PRESCALE / fmaxf(sqrtf(ss), 1e-12f);
        __hip_bfloat16 b0 = __float2bfloat16(v.x * s);
        __hip_bfloat16 b1 = __float2bfloat16(v.y * s);
        __hip_bfloat16 b2 = __float2bfloat16(v.z * s);
        __hip_bfloat16 b3 = __float2bfloat16(v.w * s);
        ushort4 o;
        o.x = *(ushort*)&b0; o.y = *(ushort*)&b1; o.z = *(ushort*)&b2; o.w = *(ushort*)&b3;
        ((ushort4*)(nbf + (size_t)row * D_SZ))[lane] = o;
    }
}

// decode tb -> (bi row-block of 128, bj2 col-block of 256), bj2 >= bi/2.
// masked = tile touches the diagonal region (first tile of its row).
__device__ __forceinline__ void decode_tile2(int tb, int& i0, int& j0, bool& masked) {
    int bi = 0, off = 0;
    while (off + (32 - (bi >> 1)) <= tb) { off += 32 - (bi >> 1); ++bi; }
    const int bj2 = (bi >> 1) + (tb - off);
    i0 = bi * 128; j0 = bj2 * 256;
    masked = (bj2 == (bi >> 1));
}

// ---------------- fused sim: 128x256 tiles, persistent -------------------
// 4 waves (2x2): wave quadrant 64 rows x 128 cols, acc 4x8 f32x4 (128 regs),
// 256 MFMAs/tile-wave. BK=64, r11 XOR-swizzled staging (A 16KB + B 32KB LDS).
// Correctness rule: keep only elements gi<gj; each kept element adds to BOTH
// row gi and col gj -> every unordered pair counted exactly once, no diag
// special cases (lower halves of masked tiles predicated to 0, ~3% waste).
__global__ __launch_bounds__(256) void sim_kernel(const ushort* __restrict__ N,
                                                  const int* __restrict__ ids,
                                                  float* __restrict__ all_sum,
                                                  float* __restrict__ pos_sum) {
    __shared__ ushort sA[128 * 64];   // A tile: 128 rows x 64-elem k-window
    __shared__ ushort sB[256 * 64];   // B tile: 256 rows x 64-elem k-window

    const int t    = threadIdx.x;
    const int wave = t >> 6, lane = t & 63;
    const int wy   = wave >> 1, wx = wave & 1;
    const int r    = lane >> 3;                     // 0..7 sub-row
    const int c8s  = ((lane & 7) ^ r) * 8;          // swizzled source chunk
    const int myc  = lane & 15;

    for (int tb = blockIdx.x; tb < NTILES2; tb += GRID_SIM) {
        int i0, j0; bool masked;
        decode_tile2(tb, i0, j0, masked);

        f32x4 acc[4][8];
        #pragma unroll
        for (int mi = 0; mi < 4; ++mi)
            #pragma unroll
            for (int ni = 0; ni < 8; ++ni)
                acc[mi][ni] = (f32x4){0.f, 0.f, 0.f, 0.f};

        for (int kk = 0; kk < 4; ++kk) {
            const int k0 = kk * 64;
            // A: wave stages 32 rows (4 instrs); B: 64 rows (8 instrs)
            const ushort* gA = N + (size_t)(i0 + wave * 32) * D_SZ + k0;
            const ushort* gB = N + (size_t)(j0 + wave * 64) * D_SZ + k0;
            #pragma unroll
            for (int q = 0; q < 4; ++q)
                async_copy16(gA + (size_t)(q * 8 + r) * D_SZ + c8s, &sA[(wave * 32 + q * 8) * 64]);
            #pragma unroll
            for (int q = 0; q < 8; ++q)
                async_copy16(gB + (size_t)(q * 8 + r) * D_SZ + c8s, &sB[(wave * 64 + q * 8) * 64]);
            __syncthreads();

            #pragma unroll
            for (int ks = 0; ks < 2; ++ks) {
                const int C = ks * 4 + (lane >> 4);     // k-chunk index 0..7
                const int slot = (C ^ (lane & 7)) * 8;  // un-swizzle
                s16x8 af[4], bf[8];
                #pragma unroll
                for (int mi = 0; mi < 4; ++mi)
                    af[mi] = *(const s16x8*)&sA[(wy * 64 + mi * 16 + (lane & 15)) * 64 + slot];
                #pragma unroll
                for (int ni = 0; ni < 8; ++ni)
                    bf[ni] = *(const s16x8*)&sB[(wx * 128 + ni * 16 + (lane & 15)) * 64 + slot];
                #pragma unroll
                for (int mi = 0; mi < 4; ++mi)
                    #pragma unroll
                    for (int ni = 0; ni < 8; ++ni)
                        acc[mi][ni] = __builtin_amdgcn_mfma_f32_16x16x32_bf16(
                            af[mi], bf[ni], acc[mi][ni], 0, 0, 0);
            }
            __syncthreads();
        }

        // ---- epilogue (registers + shuffles + global atomics) ----
        // C/D map: col=lane&15, row=(lane>>4)*4+reg (quadrant-local)
        const int R0 = i0 + wy * 64;        // global row base of this wave
        const int CB = j0 + wx * 128;       // global col base of this wave
        int idc[8];
        #pragma unroll
        for (int ni = 0; ni < 8; ++ni)
            idc[ni] = ids[CB + ni * 16 + myc];

        float cAll[8] = {0.f,0.f,0.f,0.f,0.f,0.f,0.f,0.f};
        float cPos[8] = {0.f,0.f,0.f,0.f,0.f,0.f,0.f,0.f};

        #pragma unroll
        for (int mi = 0; mi < 4; ++mi) {
            const int rbl = mi * 16 + (lane >> 4) * 4;   // wave-local row of reg 0
            const int4 idr = *(const int4*)&ids[R0 + rbl];
            float rAll[4] = {0.f, 0.f, 0.f, 0.f};
            float rPos[4] = {0.f, 0.f, 0.f, 0.f};
            #pragma unroll
            for (int ni = 0; ni < 8; ++ni) {
                const int gj = CB + ni * 16 + myc;
                #pragma unroll
                for (int rg = 0; rg < 4; ++rg) {
                    float e = __builtin_amdgcn_exp2f(acc[mi][ni][rg]);
                    if (masked && (R0 + rbl + rg) >= gj) e = 0.0f;  // keep gi<gj
                    rAll[rg] += e; cAll[ni] += e;
                    const int idrv = (rg == 0) ? idr.x : (rg == 1) ? idr.y
                                   : (rg == 2) ? idr.z : idr.w;
                    if (idrv == idc[ni]) { rPos[rg] += e; cPos[ni] += e; }
                }
            }
            #pragma unroll
            for (int rg = 0; rg < 4; ++rg) {
                #pragma unroll
                for (int mm = 1; mm < 16; mm <<= 1) {
                    rAll[rg] += __shfl_xor(rAll[rg], mm, 64);
                    rPos[rg] += __shfl_xor(rPos[rg], mm, 64);
                }
            }
            if (myc == 0) {
                #pragma unroll
                for (int rg = 0; rg < 4; ++rg) {
                    atomicAdd(&all_sum[R0 + rbl + rg], rAll[rg]);
                    if (rPos[rg] != 0.0f) atomicAdd(&pos_sum[R0 + rbl + rg], rPos[rg]);
                }
            }
        }

        // column contributions (always: kept elements feed col gj by symmetry)
        #pragma unroll
        for (int ni = 0; ni < 8; ++ni) {
            cAll[ni] += __shfl_xor(cAll[ni], 16, 64);
            cAll[ni] += __shfl_xor(cAll[ni], 32, 64);
            cPos[ni] += __shfl_xor(cPos[ni], 16, 64);
            cPos[ni] += __shfl_xor(cPos[ni], 32, 64);
        }
        if (lane < 16) {
            #pragma unroll
            for (int ni = 0; ni < 8; ++ni) {
                atomicAdd(&all_sum[CB + ni * 16 + lane], cAll[ni]);
                if (cPos[ni] != 0.0f) atomicAdd(&pos_sum[CB + ni * 16 + lane], cPos[ni]);
            }
        }
        __syncthreads();   // atomics issued; LDS reusable next tile after barrier
    }
}

// ---------------- final scalar reduce ----------------
__global__ __launch_bounds__(256) void loss_kernel(const float* __restrict__ all_sum,
                                                   const float* __restrict__ pos_sum,
                                                   float* __restrict__ out) {
    float loss = 0.0f, cnt = 0.0f;
    for (int i = threadIdx.x; i < B_SZ; i += 256) {
        float p = pos_sum[i], a = all_sum[i];
        if (p > 0.0f) { loss += logf(a) - logf(p); cnt += 1.0f; }
    }
    #pragma unroll
    for (int m = 1; m < 64; m <<= 1) {
        loss += __shfl_xor(loss, m, 64);
        cnt  += __shfl_xor(cnt, m, 64);
    }
    __shared__ float sl[4], sc[4];
    int wave = threadIdx.x >> 6, lane = threadIdx.x & 63;
    if (lane == 0) { sl[wave] = loss; sc[wave] = cnt; }
    __syncthreads();
    if (threadIdx.x == 0) {
        float L = sl[0] + sl[1] + sl[2] + sl[3];
        float C = sc[0] + sc[1] + sc[2] + sc[3];
        out[0] = L / fmaxf(C, 1.0f);
    }
}

extern "C" void kernel_launch(void* const* d_in, const int* in_sizes, int n_in,
                              void* d_out, int out_size, void* d_ws, size_t ws_size,
                              hipStream_t stream) {
    const float* emb = (const float*)d_in[0];
    const int*   ids = (const int*)d_in[1];
    float*       out = (float*)d_out;

    float*  all_sum = (float*)d_ws;
    float*  pos_sum = all_sum + B_SZ;
    ushort* nbf     = (ushort*)((char*)d_ws + 65536);   // 8192*256 bf16 = 4 MB

    norm_kernel<<<256, 256, 0, stream>>>(emb, nbf, all_sum);
    sim_kernel<<<GRID_SIM, 256, 0, stream>>>(nbf, ids, all_sum, pos_sum);
    loss_kernel<<<1, 256, 0, stream>>>(all_sum, pos_sum, out);
}

// Round 17
// 117.876 us; speedup vs baseline: 1.6361x; 1.2903x over previous
//
#include <hip/hip_runtime.h>
#include <hip/hip_bf16.h>

#define B_SZ 8192
#define D_SZ 256
#define NTILES 2080   // (8192/128)*(8192/128+1)/2 upper-tri tiles
#define GRID_SIM 512  // persistent, 2 blocks/CU (64 KB LDS)
// rows pre-scaled by sqrt(log2(e)/T): exp2(acc) == exp(sim/T)
#define PRESCALE 4.539816004686735f

typedef __attribute__((ext_vector_type(4))) float f32x4;
typedef __attribute__((ext_vector_type(8))) short s16x8;

// ---------------- L2-normalize rows, scale, cast to bf16 (+ zero sums) -----
__global__ __launch_bounds__(256) void norm_kernel(const float* __restrict__ emb,
                                                   ushort* __restrict__ nbf,
                                                   float* __restrict__ sums) {
    // zero all_sum+pos_sum: 16384 floats over 256 blocks
    sums[blockIdx.x * 64 + (threadIdx.x >> 2)] = 0.0f;

    const int wave = threadIdx.x >> 6, lane = threadIdx.x & 63;
    for (int g = blockIdx.x; g < B_SZ / 4; g += 256) {
        const int row = g * 4 + wave;
        const float4 v = ((const float4*)(emb + (size_t)row * D_SZ))[lane];
        float ss = v.x * v.x + v.y * v.y + v.z * v.z + v.w * v.w;
        #pragma unroll
        for (int m = 1; m < 64; m <<= 1) ss += __shfl_xor(ss, m, 64);
        float s = PRESCALE / fmaxf(sqrtf(ss), 1e-12f);
        __hip_bfloat16 b0 = __float2bfloat16(v.x * s);
        __hip_bfloat16 b1 = __float2bfloat16(v.y * s);
        __hip_bfloat16 b2 = __float2bfloat16(v.z * s);
        __hip_bfloat16 b3 = __float2bfloat16(v.w * s);
        ushort4 o;
        o.x = *(ushort*)&b0; o.y = *(ushort*)&b1; o.z = *(ushort*)&b2; o.w = *(ushort*)&b3;
        ((ushort4*)(nbf + (size_t)row * D_SZ))[lane] = o;
    }
}

// ---------------- helpers ---------------------------------------------------
__device__ __forceinline__ void decode_tile(int tb, int& i0, int& j0, bool& diag) {
    int bj = (int)((sqrtf(8.0f * tb + 1.0f) - 1.0f) * 0.5f);
    while ((bj + 1) * (bj + 2) / 2 <= tb) ++bj;
    while (bj * (bj + 1) / 2 > tb) --bj;
    const int bi = tb - bj * (bj + 1) / 2;
    i0 = bi * 128; j0 = bj * 128; diag = (bi == bj);
}

// global -> VGPR staging (exact vmcnt tracking; loads may cross barriers).
// Lane pattern identical to the old DMA (row q*8+r, swizzled chunk c8s).
__device__ __forceinline__ void load_regs(s16x8 ra[4], s16x8 rb[4],
                                          const ushort* __restrict__ N,
                                          int i0, int j0, int k0,
                                          int wave, int r, int c8s) {
    const ushort* gA = N + (size_t)(i0 + wave * 32) * D_SZ + k0;
    const ushort* gB = N + (size_t)(j0 + wave * 32) * D_SZ + k0;
    #pragma unroll
    for (int q = 0; q < 4; ++q) {
        ra[q] = *(const s16x8*)(gA + (size_t)(q * 8 + r) * D_SZ + c8s);
        rb[q] = *(const s16x8*)(gB + (size_t)(q * 8 + r) * D_SZ + c8s);
    }
}

// VGPR -> LDS: lane writes its 16B at base + lane*16 (matches DMA layout:
// LDS row wave*32+q*8+(lane>>3), slot lane&7 holds source chunk (lane&7)^r).
__device__ __forceinline__ void store_stage(const s16x8 ra[4], const s16x8 rb[4],
                                            ushort* bA, ushort* bB,
                                            int wave, int lane) {
    #pragma unroll
    for (int q = 0; q < 4; ++q) {
        *(s16x8*)&bA[(wave * 32 + q * 8) * 64 + lane * 8] = ra[q];
        *(s16x8*)&bB[(wave * 32 + q * 8) * 64 + lane * 8] = rb[q];
    }
}

// ---------------- fused sim: VGPR-staged pipeline, persistent tiles --------
// Per stage: ds_write(regs k) [waits aged vmcnt] -> issue loads k+1 ->
// __syncthreads [lgkm only -- loads stay IN FLIGHT across the barrier] ->
// ds_read + MFMA. Double-buffered LDS (64 KB); buffer parity makes one
// barrier per stage sufficient. Epilogue = r11 (partials in buf0 region).
__global__ __launch_bounds__(256) void sim_kernel(const ushort* __restrict__ N,
                                                  const int* __restrict__ ids,
                                                  float* __restrict__ all_sum,
                                                  float* __restrict__ pos_sum) {
    __shared__ ushort smem[4 * 128 * 64];   // A0|B0|A1|B1, 16 KB each

    const int t    = threadIdx.x;
    const int wave = t >> 6, lane = t & 63;
    const int wy   = wave >> 1, wx = wave & 1;
    const int r    = lane >> 3;                     // 0..7 sub-row
    const int c8s  = ((lane & 7) ^ r) * 8;          // swizzled source chunk
    const int myc  = lane & 15;

    int tb = blockIdx.x;
    int i0, j0; bool diag;
    decode_tile(tb, i0, j0, diag);

    s16x8 ra[4], rb[4];
    load_regs(ra, rb, N, i0, j0, 0, wave, r, c8s);

    while (true) {
        const int ntb = tb + GRID_SIM;
        const bool have_next = (ntb < NTILES);
        int ni0 = i0, nj0 = j0; bool ndiag = diag;
        if (have_next) decode_tile(ntb, ni0, nj0, ndiag);

        f32x4 acc[4][4];
        #pragma unroll
        for (int mi = 0; mi < 4; ++mi)
            #pragma unroll
            for (int ni = 0; ni < 4; ++ni)
                acc[mi][ni] = (f32x4){0.f, 0.f, 0.f, 0.f};

        #pragma unroll
        for (int kk = 0; kk < 4; ++kk) {
            ushort* bA = smem + (kk & 1) * 16384;   // 2*128*64 ushorts = 16384
            ushort* bB = bA + 8192;
            store_stage(ra, rb, bA, bB, wave, lane);
            if (kk < 3)           load_regs(ra, rb, N, i0, j0, (kk + 1) * 64, wave, r, c8s);
            else if (have_next)   load_regs(ra, rb, N, ni0, nj0, 0, wave, r, c8s);
            __syncthreads();      // lgkm drain; new global loads stay in flight

            #pragma unroll
            for (int ks = 0; ks < 2; ++ks) {
                const int C = ks * 4 + (lane >> 4);     // k-chunk index 0..7
                const int slot = (C ^ (lane & 7)) * 8;  // un-swizzle
                s16x8 af[4], bf[4];
                #pragma unroll
                for (int mi = 0; mi < 4; ++mi)
                    af[mi] = *(const s16x8*)&bA[(wy * 64 + mi * 16 + (lane & 15)) * 64 + slot];
                #pragma unroll
                for (int ni = 0; ni < 4; ++ni)
                    bf[ni] = *(const s16x8*)&bB[(wx * 64 + ni * 16 + (lane & 15)) * 64 + slot];
                #pragma unroll
                for (int mi = 0; mi < 4; ++mi)
                    #pragma unroll
                    for (int ni = 0; ni < 4; ++ni)
                        acc[mi][ni] = __builtin_amdgcn_mfma_f32_16x16x32_bf16(
                            af[mi], bf[ni], acc[mi][ni], 0, 0, 0);
            }
            // WAR safety: buf (kk&1) is next written at stage kk+2, which is
            // after barrier kk+1 -- all waves' reads of it are complete then.
        }

        // ---- epilogue (r11).  C/D map: col=lane&15, row=(lane>>4)*4+reg ----
        // Partials live in buf0 region (A0=rowAll, B0=rowPos): buf0 was last
        // read at stage kk=2; barrier kk=3 separates -> safe.
        float* rowAllPart = (float*)smem;            // [128][32]
        float* rowPosPart = (float*)&smem[8192];     // [128][32]

        int idc[4];
        #pragma unroll
        for (int ni = 0; ni < 4; ++ni)
            idc[ni] = ids[j0 + wx * 64 + ni * 16 + myc];

        float cAll[4] = {0.f, 0.f, 0.f, 0.f};
        float cPos[4] = {0.f, 0.f, 0.f, 0.f};

        #pragma unroll
        for (int mi = 0; mi < 4; ++mi) {
            float rAll[4] = {0.f, 0.f, 0.f, 0.f};
            float rPos[4] = {0.f, 0.f, 0.f, 0.f};
            const int rbase = wy * 64 + mi * 16 + (lane >> 4) * 4;
            const int4 idr  = *(const int4*)&ids[i0 + rbase];
            #pragma unroll
            for (int ni = 0; ni < 4; ++ni) {
                const int cloc = wx * 64 + ni * 16 + myc;
                #pragma unroll
                for (int rg = 0; rg < 4; ++rg) {
                    const int lr = rbase + rg;
                    float e = __builtin_amdgcn_exp2f(acc[mi][ni][rg]);
                    if (diag && lr == cloc) e = 0.0f;        // diagonal element
                    rAll[rg] += e; cAll[ni] += e;
                    const int idrv = (rg == 0) ? idr.x : (rg == 1) ? idr.y
                                   : (rg == 2) ? idr.z : idr.w;
                    if (idrv == idc[ni]) { rPos[rg] += e; cPos[ni] += e; }
                }
            }
            #pragma unroll
            for (int rg = 0; rg < 4; ++rg) {
                rowAllPart[(rbase + rg) * 32 + wx * 16 + myc] = rAll[rg];
                rowPosPart[(rbase + rg) * 32 + wx * 16 + myc] = rPos[rg];
            }
        }

        // column sums -> rows j (off-diagonal tiles only; symmetry)
        if (!diag) {
            #pragma unroll
            for (int ni = 0; ni < 4; ++ni) {
                cAll[ni] += __shfl_xor(cAll[ni], 16, 64);
                cAll[ni] += __shfl_xor(cAll[ni], 32, 64);
                cPos[ni] += __shfl_xor(cPos[ni], 16, 64);
                cPos[ni] += __shfl_xor(cPos[ni], 32, 64);
            }
            if (lane < 16) {
                #pragma unroll
                for (int ni = 0; ni < 4; ++ni) {
                    const int gc = j0 + wx * 64 + ni * 16 + lane;
                    atomicAdd(&all_sum[gc], cAll[ni]);
                    if (cPos[ni] != 0.0f) atomicAdd(&pos_sum[gc], cPos[ni]);
                }
            }
        }

        __syncthreads();
        // row partial reduce: thread t -> (row = t&127, array = t>>7)
        {
            const int row = t & 127;
            const float* src = (t >= 128) ? rowPosPart : rowAllPart;
            float s = 0.0f;
            #pragma unroll
            for (int k8 = 0; k8 < 8; ++k8) {
                const int chunk = (k8 + (row & 7)) & 7;
                const float4 v = *(const float4*)&src[row * 32 + chunk * 4];
                s += v.x + v.y + v.z + v.w;
            }
            float* dst = (t >= 128) ? pos_sum : all_sum;
            atomicAdd(&dst[i0 + row], s);
        }
        __syncthreads();   // partials consumed; buf0 reusable next tile

        if (!have_next) break;
        tb = ntb; i0 = ni0; j0 = nj0; diag = ndiag;
    }
}

// ---------------- final scalar reduce ----------------
__global__ __launch_bounds__(256) void loss_kernel(const float* __restrict__ all_sum,
                                                   const float* __restrict__ pos_sum,
                                                   float* __restrict__ out) {
    float loss = 0.0f, cnt = 0.0f;
    for (int i = threadIdx.x; i < B_SZ; i += 256) {
        float p = pos_sum[i], a = all_sum[i];
        if (p > 0.0f) { loss += logf(a) - logf(p); cnt += 1.0f; }
    }
    #pragma unroll
    for (int m = 1; m < 64; m <<= 1) {
        loss += __shfl_xor(loss, m, 64);
        cnt  += __shfl_xor(cnt, m, 64);
    }
    __shared__ float sl[4], sc[4];
    int wave = threadIdx.x >> 6, lane = threadIdx.x & 63;
    if (lane == 0) { sl[wave] = loss; sc[wave] = cnt; }
    __syncthreads();
    if (threadIdx.x == 0) {
        float L = sl[0] + sl[1] + sl[2] + sl[3];
        float C = sc[0] + sc[1] + sc[2] + sc[3];
        out[0] = L / fmaxf(C, 1.0f);
    }
}

extern "C" void kernel_launch(void* const* d_in, const int* in_sizes, int n_in,
                              void* d_out, int out_size, void* d_ws, size_t ws_size,
                              hipStream_t stream) {
    const float* emb = (const float*)d_in[0];
    const int*   ids = (const int*)d_in[1];
    float*       out = (float*)d_out;

    float*  all_sum = (float*)d_ws;
    float*  pos_sum = all_sum + B_SZ;
    ushort* nbf     = (ushort*)((char*)d_ws + 65536);   // 8192*256 bf16 = 4 MB

    norm_kernel<<<256, 256, 0, stream>>>(emb, nbf, all_sum);
    sim_kernel<<<GRID_SIM, 256, 0, stream>>>(nbf, ids, all_sum, pos_sum);
    loss_kernel<<<1, 256, 0, stream>>>(all_sum, pos_sum, out);
}